// Round 4
// baseline (438.881 us; speedup 1.0000x reference)
//
#include <hip/hip_runtime.h>
#include <cstdint>
#include <cstddef>

// Problem constants
#define B_ 4
#define S_ 2048
#define E_ 1024
#define H_ 16
#define D_ 64
#define M_ (B_*S_)                        // 8192 tokens
#define NE_ ((size_t)B_*H_*S_*D_)         // 8388608 elements per q/k/v buffer

typedef unsigned int  u32;
typedef unsigned short u16;
typedef __attribute__((ext_vector_type(8))) short bf16x8;
typedef __attribute__((ext_vector_type(4))) float f32x4;
typedef __attribute__((ext_vector_type(2))) unsigned int u32x2;

// fp32 -> bf16 (round-to-nearest-even), finite inputs
__device__ __forceinline__ u16 f2bf(float x) {
    u32 u = __float_as_uint(x);
    u32 r = (u + 0x7FFFu + ((u >> 16) & 1u)) >> 16;
    return (u16)r;
}
__device__ __forceinline__ float bf2f(u16 h) { return __uint_as_float((u32)h << 16); }

// packed fp32x2 -> bf16x2 (RNE), single VOP3 instruction (T12 recipe)
__device__ __forceinline__ u32 cvtpk_bf16(float lo, float hi) {
    u32 r;
    asm("v_cvt_pk_bf16_f32 %0, %1, %2" : "=v"(r) : "v"(lo), "v"(hi));
    return r;
}

// async global->LDS 16B DMA: per-lane global addr, wave-uniform LDS base;
// HW writes lane i at ldsbase + i*16 (linear).
__device__ __forceinline__ void gload_lds16(const void* gsrc, void* lds) {
    __builtin_amdgcn_global_load_lds(
        (const __attribute__((address_space(1))) u32*)gsrc,
        (__attribute__((address_space(3))) u32*)lds, 16, 0, 0);
}

// Swizzled 64x64 bf16 tile image layout (8 KB per tile):
//   element offset = r*64 + ((c ^ (r&7))<<3) + (k&7),  r = row 0..63, c = (k>>3)
// Fragment read (16x16x32 MFMA): row r, chunk c_log = kk*4+quad, c_phys = c_log ^ (r&7).

// ---------------------------------------------------------------------------
// convert fp32 matrix (rows x 1024, row-major) -> hi/lo swizzled tile images
// [row-tile][k-tile]; one block per 64x64 tile; blockIdx.x = nt*16 + kt.
// Used for x (8192 rows), w_qkv (3072 rows), w_proj (1024 rows).
// ---------------------------------------------------------------------------
__global__ __launch_bounds__(256)
void convert_img(const float* __restrict__ src, u16* __restrict__ dh, u16* __restrict__ dl)
{
    const int tile = blockIdx.x;
    const int nt = tile >> 4, kt = tile & 15;
    const size_t tb = (size_t)tile << 12;          // u16 elements
    #pragma unroll
    for (int u = 0; u < 2; ++u) {
        const int ci = threadIdx.x + u * 256;      // 0..511
        const int r  = ci >> 3;                    // 0..63
        const int c  = ci & 7;
        const float* s = src + ((size_t)(nt * 64 + r)) * 1024 + kt * 64 + c * 8;
        const float4 f0 = *(const float4*)s;
        const float4 f1 = *(const float4*)(s + 4);
        const float vals[8] = {f0.x, f0.y, f0.z, f0.w, f1.x, f1.y, f1.z, f1.w};
        __align__(16) short hs[8];
        __align__(16) short ls[8];
        #pragma unroll
        for (int j = 0; j < 8; ++j) {
            const u16 h = f2bf(vals[j]);
            hs[j] = (short)h;
            ls[j] = (short)f2bf(vals[j] - bf2f(h));
        }
        const size_t eoff = tb + r * 64 + ((size_t)(c ^ (r & 7)) << 3);
        *(bf16x8*)(dh + eoff) = *(const bf16x8*)hs;
        *(bf16x8*)(dl + eoff) = *(const bf16x8*)ls;
    }
}

// ---------------------------------------------------------------------------
// MFMA GEMM, hi/lo 3-product bf16, PURE-DMA both operands.
// BM=128, BN=128, BK=64, 4 waves in 2x2 (each wave: 64x64 out, 4x4 16-tiles).
// A/B are pre-swizzled hi/lo tile images [row-tile][k-tile].
// MODE 0 (QKV): epilogue scatters q (natural, scaled) / kh, vh+vl (images).
// MODE 1 (proj): epilogue plain fp32 + bias.
// ---------------------------------------------------------------------------
template<int MODE>
__global__ __launch_bounds__(256)
void gemm_mfma(const u16* __restrict__ AIh, const u16* __restrict__ AIl,
               const u16* __restrict__ BIh, const u16* __restrict__ BIl,
               const float* __restrict__ bias, float* __restrict__ Cout,
               u16* __restrict__ qh, u16* __restrict__ ql,
               u16* __restrict__ kh,
               u16* __restrict__ vh, u16* __restrict__ vl)
{
    __shared__ __align__(16) u16 sA[2][2][4096];   // [row-sub][hi/lo] 32 KB
    __shared__ __align__(16) u16 sB[2][2][4096];   // [col-sub][hi/lo] 32 KB

    const int tid = threadIdx.x, lane = tid & 63, w = tid >> 6;
    const int quad = lane >> 4, l15 = lane & 15;
    const int m0  = blockIdx.x * 128;
    const int n0  = blockIdx.y * 128;
    const int mt0 = blockIdx.x * 2;                // A row-tile base
    const int nt0 = blockIdx.y * 2;                // B row-tile base
    const int rw  = w >> 1;                        // wave's row half (A sub-tile)
    const int cw  = w & 1;                         // wave's col half (B sub-tile)

    // DMA assignment: wave w stages {A-sub (w&1)} if w<2 else {B-sub (w&1)},
    // both hi and lo planes (2 x 8 KB per wave).
    const int isB = w >> 1;
    const int sbw = w & 1;

    f32x4 acc[4][4];
    #pragma unroll
    for (int i = 0; i < 4; ++i)
        #pragma unroll
        for (int j = 0; j < 4; ++j)
            acc[i][j] = (f32x4){0.f, 0.f, 0.f, 0.f};

    for (int kt = 0; kt < 16; ++kt) {
        __syncthreads();
        {   // ---- pure-DMA staging: 16 gload_lds16 per thread ----
            const size_t atile = ((size_t)((mt0 + sbw) * 16 + kt)) << 12;  // u16
            const size_t btile = ((size_t)((nt0 + sbw) * 16 + kt)) << 12;
            const u16* srcH = isB ? (BIh + btile) : (AIh + atile);
            const u16* srcL = isB ? (BIl + btile) : (AIl + atile);
            u16* dstH = isB ? &sB[sbw][0][0] : &sA[sbw][0][0];
            u16* dstL = isB ? &sB[sbw][1][0] : &sA[sbw][1][0];
            #pragma unroll
            for (int it = 0; it < 8; ++it)
                gload_lds16(srcH + it * 512 + lane * 8, dstH + it * 512);
            #pragma unroll
            for (int it = 0; it < 8; ++it)
                gload_lds16(srcL + it * 512 + lane * 8, dstL + it * 512);
        }
        __syncthreads();   // DMA drained (vmcnt at barrier)

        // ---- compute: 2 kk-steps x (4i x 4j) x 3 products = 96 MFMA ----
        #pragma unroll
        for (int kk = 0; kk < 2; ++kk) {
            bf16x8 aH[4], aL[4], bH[4], bL[4];
            #pragma unroll
            for (int i = 0; i < 4; ++i) {
                const int r = i * 16 + l15;
                const int off = r * 64 + (((kk * 4 + quad) ^ (r & 7)) << 3);
                aH[i] = *(const bf16x8*)&sA[rw][0][off];
                aL[i] = *(const bf16x8*)&sA[rw][1][off];
            }
            #pragma unroll
            for (int j = 0; j < 4; ++j) {
                const int r = j * 16 + l15;
                const int off = r * 64 + (((kk * 4 + quad) ^ (r & 7)) << 3);
                bH[j] = *(const bf16x8*)&sB[cw][0][off];
                bL[j] = *(const bf16x8*)&sB[cw][1][off];
            }
            #pragma unroll
            for (int i = 0; i < 4; ++i)
                #pragma unroll
                for (int j = 0; j < 4; ++j) {
                    acc[i][j] = __builtin_amdgcn_mfma_f32_16x16x32_bf16(aL[i], bH[j], acc[i][j], 0, 0, 0);
                    acc[i][j] = __builtin_amdgcn_mfma_f32_16x16x32_bf16(aH[i], bL[j], acc[i][j], 0, 0, 0);
                    acc[i][j] = __builtin_amdgcn_mfma_f32_16x16x32_bf16(aH[i], bH[j], acc[i][j], 0, 0, 0);
                }
        }
    }

    // ---- epilogue ----
    const int fbase = n0 + cw * 64;                // 64-aligned
    float bj[4];
    #pragma unroll
    for (int j = 0; j < 4; ++j) bj[j] = bias[fbase + j * 16 + l15];

    if (MODE == 0) {
        const int cR = fbase >> 10;                // 0=q 1=k 2=v (uniform per wave)
        const int hh = (fbase >> 6) & 15;
        #pragma unroll
        for (int i = 0; i < 4; ++i)
            #pragma unroll
            for (int j = 0; j < 4; ++j)
                #pragma unroll
                for (int reg = 0; reg < 4; ++reg) {
                    float val = acc[i][j][reg] + bj[j];
                    const int m = m0 + rw * 64 + i * 16 + quad * 4 + reg;
                    const int d = j * 16 + l15;
                    const int bb = m >> 11, s = m & 2047;
                    const int bh = bb * 16 + hh;
                    // q scale = 0.125 * log2(e): softmax uses exp2 directly.
                    if (cR == 0) val *= 0.18033688011112042f;
                    const u16 h = f2bf(val);
                    if (cR == 0) {
                        const u16 lo = f2bf(val - bf2f(h));
                        const size_t idx = ((size_t)bh * 2048 + s) * 64 + d;
                        qh[idx] = h; ql[idx] = lo;
                    } else if (cR == 1) {
                        // k-lo not consumed (2-product QK) -> only hi written
                        const size_t tile = (size_t)bh * 32 + (s >> 6);
                        const int r = s & 63;
                        const size_t off = (tile << 12) + r * 64 + (((d >> 3) ^ (r & 7)) << 3) + (d & 7);
                        kh[off] = h;
                    } else {
                        const u16 lo = f2bf(val - bf2f(h));
                        const size_t tile = (size_t)bh * 32 + (s >> 6);
                        const size_t off = (tile << 12) + d * 64 + ((((s & 63) >> 3) ^ (d & 7)) << 3) + (s & 7);
                        vh[off] = h; vl[off] = lo;
                    }
                }
    } else {
        #pragma unroll
        for (int i = 0; i < 4; ++i)
            #pragma unroll
            for (int j = 0; j < 4; ++j)
                #pragma unroll
                for (int reg = 0; reg < 4; ++reg) {
                    const int m = m0 + rw * 64 + i * 16 + quad * 4 + reg;
                    const int f = fbase + j * 16 + l15;
                    Cout[(size_t)m * 1024 + f] = acc[i][j][reg] + bj[j];
                }
    }
}

// ---------------------------------------------------------------------------
// MFMA flash attention, FIXED-MAX softmax (folded into acc init), exp2 form.
// Round 8: in-register P transpose (T12 full form) -- Psh LDS round-trip
// eliminated.
//   QK swapped:  Ssw = mfma(K, Qlo) + mfma(K, Qhi)  ->  lane holds
//                P[k = ks*16+quad*4+reg][q = l15]  (q lane-local).
//   P -> PV operand: pack pairs with v_cvt_pk_bf16_f32, then
//   (W0,W2) = permlane16_swap(permlane32_swap(u0,v0)),  (W1,W3) from (u1,v1)
//   gives PA[q=l15][k = kk*32+quad*8+j] exactly (derivation in journal).
//   PV swapped:  O^T = mfma(Vt, PA)  (V image already transposed) ->
//                lane holds O[d = ds*16+quad*4+reg][q = l15].
//   l: per-lane partial over local k, one xor16+xor32 reduce at end.
// LDS 24 KB (Psh gone); launch_bounds(256,3) (do NOT cap VGPRs harder:
// round-2 showed (256,4) forces spills).
// ---------------------------------------------------------------------------
__global__ __launch_bounds__(256, 3)
void attn_mfma(const u16* __restrict__ qh, const u16* __restrict__ ql,
               const u16* __restrict__ kh,
               const u16* __restrict__ vh, const u16* __restrict__ vl,
               u16* __restrict__ oh, u16* __restrict__ ol)
{
    __shared__ __align__(16) u16 KV[3][4096];     // Khi Vthi Vtlo (24 KB)

    const int tid  = threadIdx.x;
    const int lane = tid & 63, w = tid >> 6;
    const int quad = lane >> 4, l15 = lane & 15;
    const int bh = blockIdx.y;
    const int q0 = blockIdx.x * 128 + w * 32;

    bf16x8 Qf[2][2][2];
    #pragma unroll
    for (int qs = 0; qs < 2; ++qs)
        #pragma unroll
        for (int kk = 0; kk < 2; ++kk) {
            const size_t idx = ((size_t)bh * S_ + q0 + qs * 16 + l15) * 64 + kk * 32 + quad * 8;
            Qf[qs][kk][0] = *(const bf16x8*)(qh + idx);
            Qf[qs][kk][1] = *(const bf16x8*)(ql + idx);
        }

    f32x4 O[2][4];
    float l_part[2] = {0.f, 0.f};
    #pragma unroll
    for (int qs = 0; qs < 2; ++qs)
        #pragma unroll
        for (int ds = 0; ds < 4; ++ds)
            O[qs][ds] = (f32x4){0.f, 0.f, 0.f, 0.f};

    const char* gk[3] = {(const char*)kh, (const char*)vh, (const char*)vl};

    for (int kt = 0; kt < S_ / 64; ++kt) {
        __syncthreads();
        const size_t tb = (((size_t)bh * 32 + kt) << 13);
        #pragma unroll
        for (int a = 0; a < 3; ++a)
            #pragma unroll
            for (int it = 0; it < 2; ++it) {
                const int off = w * 2048 + it * 1024;
                gload_lds16(gk[a] + tb + off + lane * 16, (char*)&KV[a][0] + off);
            }
        __syncthreads();

        // ---- swapped QK:  Ssw[m=k][n=q],  init = -16*log2(e) (fixed max) ----
        f32x4 S[2][4];
        #pragma unroll
        for (int qs = 0; qs < 2; ++qs)
            #pragma unroll
            for (int ks = 0; ks < 4; ++ks)
                S[qs][ks] = (f32x4){-23.083120654223414f, -23.083120654223414f,
                                    -23.083120654223414f, -23.083120654223414f};

        __builtin_amdgcn_s_setprio(1);
        #pragma unroll
        for (int ks = 0; ks < 4; ++ks) {
            const int r = ks * 16 + l15;
            #pragma unroll
            for (int kk = 0; kk < 2; ++kk) {
                const int c = (kk * 4 + quad) ^ (r & 7);
                const bf16x8 Kh = *(const bf16x8*)&KV[0][r * 64 + c * 8];
                #pragma unroll
                for (int qs = 0; qs < 2; ++qs) {
                    S[qs][ks] = __builtin_amdgcn_mfma_f32_16x16x32_bf16(Kh, Qf[qs][kk][1], S[qs][ks], 0, 0, 0);
                    S[qs][ks] = __builtin_amdgcn_mfma_f32_16x16x32_bf16(Kh, Qf[qs][kk][0], S[qs][ks], 0, 0, 0);
                }
            }
        }
        __builtin_amdgcn_s_setprio(0);

        // ---- softmax + in-register transpose to PV operand layout ----
        u32 PA[2][2][4];     // [qs][kk][word]
        #pragma unroll
        for (int qs = 0; qs < 2; ++qs) {
            float lsum = 0.f;
            u32 PK[4][2];
            #pragma unroll
            for (int ks = 0; ks < 4; ++ks) {
                const float p0 = __builtin_exp2f(S[qs][ks][0]);
                const float p1 = __builtin_exp2f(S[qs][ks][1]);
                const float p2 = __builtin_exp2f(S[qs][ks][2]);
                const float p3 = __builtin_exp2f(S[qs][ks][3]);
                lsum += (p0 + p1) + (p2 + p3);
                PK[ks][0] = cvtpk_bf16(p0, p1);
                PK[ks][1] = cvtpk_bf16(p2, p3);
            }
            l_part[qs] += lsum;
            #pragma unroll
            for (int kk = 0; kk < 2; ++kk) {
                const u32x2 t0 = __builtin_amdgcn_permlane32_swap(PK[2 * kk][0], PK[2 * kk + 1][0], false, false);
                const u32x2 w02 = __builtin_amdgcn_permlane16_swap(t0.x, t0.y, false, false);
                const u32x2 t1 = __builtin_amdgcn_permlane32_swap(PK[2 * kk][1], PK[2 * kk + 1][1], false, false);
                const u32x2 w13 = __builtin_amdgcn_permlane16_swap(t1.x, t1.y, false, false);
                PA[qs][kk][0] = w02.x;
                PA[qs][kk][1] = w13.x;
                PA[qs][kk][2] = w02.y;
                PA[qs][kk][3] = w13.y;
            }
        }

        // ---- swapped PV:  O^T += Vt x PA  (two products: Vlo, Vhi) ----
        __builtin_amdgcn_s_setprio(1);
        #pragma unroll
        for (int kk = 0; kk < 2; ++kk) {
            union { u32 w4[4]; bf16x8 v; } pu0, pu1;
            #pragma unroll
            for (int c = 0; c < 4; ++c) { pu0.w4[c] = PA[0][kk][c]; pu1.w4[c] = PA[1][kk][c]; }
            const bf16x8 paf[2] = {pu0.v, pu1.v};
            #pragma unroll
            for (int ds = 0; ds < 4; ++ds) {
                const int r = ds * 16 + l15;
                const int c = (kk * 4 + quad) ^ (r & 7);
                const bf16x8 Vh = *(const bf16x8*)&KV[1][r * 64 + c * 8];
                const bf16x8 Vl = *(const bf16x8*)&KV[2][r * 64 + c * 8];
                #pragma unroll
                for (int qs = 0; qs < 2; ++qs) {
                    O[qs][ds] = __builtin_amdgcn_mfma_f32_16x16x32_bf16(Vl, paf[qs], O[qs][ds], 0, 0, 0);
                    O[qs][ds] = __builtin_amdgcn_mfma_f32_16x16x32_bf16(Vh, paf[qs], O[qs][ds], 0, 0, 0);
                }
            }
        }
        __builtin_amdgcn_s_setprio(0);
    }

    // ---- l reduction across quads (k partials live on lanes l15, +16, +32, +48)
    float linv[2];
    #pragma unroll
    for (int qs = 0; qs < 2; ++qs) {
        float rs = l_part[qs];
        rs += __shfl_xor(rs, 16);
        rs += __shfl_xor(rs, 32);
        linv[qs] = 1.f / rs;
    }

    // ---- epilogue: lane holds O[d = ds*16+quad*4+reg][q = l15] ----
    const int bb = bh >> 4, hh = bh & 15;
    #pragma unroll
    for (int qs = 0; qs < 2; ++qs) {
        const float inv = linv[qs];
        const int s = q0 + qs * 16 + l15;
        const int m = bb * 2048 + s;
        const int mt = m >> 6, r = m & 63;
        const size_t tbase = ((size_t)(mt * 16 + hh)) << 12;
        #pragma unroll
        for (int ds = 0; ds < 4; ++ds) {
            const int d0 = ds * 16 + quad * 4;     // 4 consecutive d per thread
            const float v0 = O[qs][ds][0] * inv;
            const float v1 = O[qs][ds][1] * inv;
            const float v2 = O[qs][ds][2] * inv;
            const float v3 = O[qs][ds][3] * inv;
            const u32 h01 = cvtpk_bf16(v0, v1);
            const u32 h23 = cvtpk_bf16(v2, v3);
            const float r0 = v0 - bf2f((u16)h01);
            const float r1 = v1 - bf2f((u16)(h01 >> 16));
            const float r2 = v2 - bf2f((u16)h23);
            const float r3 = v3 - bf2f((u16)(h23 >> 16));
            const u32 l01 = cvtpk_bf16(r0, r1);
            const u32 l23 = cvtpk_bf16(r2, r3);
            // image offset: d0&7 in {0,4}; 4 u16 contiguous, 8B-aligned
            const size_t off = tbase + r * 64 + (size_t)((((d0 >> 3) ^ (r & 7)) << 3) + (d0 & 7));
            *(u32x2*)(oh + off) = (u32x2){h01, h23};
            *(u32x2*)(ol + off) = (u32x2){l01, l23};
        }
    }
}

// ---------------------------------------------------------------------------
extern "C" void kernel_launch(void* const* d_in, const int* in_sizes, int n_in,
                              void* d_out, int out_size, void* d_ws, size_t ws_size,
                              hipStream_t stream) {
    const float* x      = (const float*)d_in[0];
    const float* w_qkv  = (const float*)d_in[1];
    const float* b_qkv  = (const float*)d_in[2];
    const float* w_proj = (const float*)d_in[3];
    const float* b_proj = (const float*)d_in[4];
    float* out = (float*)d_out;

    // ws (130 MB, < proven-safe 134 MB):
    //   [0..5NE_)        qh ql kh vh vl
    //   [5NE_..7NE_)     xh xl (phase 0-1)  -> aliased by oh ol (phase 2+)
    //   [7NE_..)         wqh wql (6.29M u16, phase 0-1) -> aliased by wph wpl
    u16* qh  = (u16*)d_ws;
    u16* ql  = qh + NE_;
    u16* kh  = ql + NE_;
    u16* vh  = kh + NE_;
    u16* vl  = vh + NE_;
    u16* xh  = vl + NE_;
    u16* xl  = xh + NE_;
    u16* wqh = xl + NE_;
    u16* wql = wqh + (size_t)3 * 1024 * 1024;
    u16* oh  = xh;                         // alias (x dead after QKV)
    u16* ol  = xl;
    u16* wph = wqh;                        // alias (wq dead after QKV)
    u16* wpl = wph + (size_t)1024 * 1024;

    // Phase 0: one-time conversions to hi/lo swizzled tile images
    convert_img<<<(M_ / 64) * 16, 256, 0, stream>>>(x, xh, xl);          // 2048 tiles
    convert_img<<<48 * 16, 256, 0, stream>>>(w_qkv, wqh, wql);           // 768 tiles

    {   // Phase 1: QKV GEMM (pure-DMA MFMA): x @ w_qkv^T + b -> q/k/v
        dim3 grid(M_ / 128, (3 * E_) / 128);   // 64 x 24
        gemm_mfma<0><<<grid, 256, 0, stream>>>(xh, xl, wqh, wql,
                                               b_qkv, nullptr, qh, ql, kh, vh, vl);
    }
    {   // Phase 2: MFMA flash attention -> o-tile images (overwrites x images)
        dim3 grid(S_ / 128, B_ * H_);          // 16 x 64
        attn_mfma<<<grid, 256, 0, stream>>>(qh, ql, kh, vh, vl, oh, ol);
    }
    // Phase 2.5: convert w_proj (overwrites wq images)
    convert_img<<<16 * 16, 256, 0, stream>>>(w_proj, wph, wpl);          // 256 tiles
    {   // Phase 3: proj GEMM (pure-DMA MFMA): o @ w_proj^T + b -> out
        dim3 grid(M_ / 128, E_ / 128);         // 64 x 8
        gemm_mfma<1><<<grid, 256, 0, stream>>>(oh, ol, wph, wpl,
                                               b_proj, out, nullptr, nullptr, nullptr,
                                               nullptr, nullptr);
    }
}

// Round 5
// 429.858 us; speedup vs baseline: 1.0210x; 1.0210x over previous
//
#include <hip/hip_runtime.h>
#include <cstdint>
#include <cstddef>

// Problem constants
#define B_ 4
#define S_ 2048
#define E_ 1024
#define H_ 16
#define D_ 64
#define M_ (B_*S_)                        // 8192 tokens
#define NE_ ((size_t)B_*H_*S_*D_)         // 8388608 elements per q/k/v buffer

typedef unsigned int  u32;
typedef unsigned short u16;
typedef __attribute__((ext_vector_type(8))) short bf16x8;
typedef __attribute__((ext_vector_type(4))) float f32x4;
typedef __attribute__((ext_vector_type(2))) unsigned int u32x2;

// fp32 -> bf16 (round-to-nearest-even), finite inputs
__device__ __forceinline__ u16 f2bf(float x) {
    u32 u = __float_as_uint(x);
    u32 r = (u + 0x7FFFu + ((u >> 16) & 1u)) >> 16;
    return (u16)r;
}
__device__ __forceinline__ float bf2f(u16 h) { return __uint_as_float((u32)h << 16); }

// packed fp32x2 -> bf16x2 (RNE), single VOP3 instruction (T12 recipe)
__device__ __forceinline__ u32 cvtpk_bf16(float lo, float hi) {
    u32 r;
    asm("v_cvt_pk_bf16_f32 %0, %1, %2" : "=v"(r) : "v"(lo), "v"(hi));
    return r;
}

// async global->LDS 16B DMA: per-lane global addr, wave-uniform LDS base;
// HW writes lane i at ldsbase + i*16 (linear).
__device__ __forceinline__ void gload_lds16(const void* gsrc, void* lds) {
    __builtin_amdgcn_global_load_lds(
        (const __attribute__((address_space(1))) u32*)gsrc,
        (__attribute__((address_space(3))) u32*)lds, 16, 0, 0);
}

// ---------------------------------------------------------------------------
// TWO image formats:
//
// k64 tile (old, 64x64, 8 KB) -- used for K and V (attn kernel unchanged):
//   offset = r*64 + ((c ^ (r&7))<<3) + (k&7),  c = k>>3.
//
// k32 tile (new, 64 rows x 32 k, 4 KB) -- used for all GEMM operands
// (x, w_qkv, w_proj, o). BK=32 GEMM K-step:
//   l = r>>1,  s = (r&1)*4 + (k>>3),  ph = s ^ (l&7)
//   offset = l*64 + ph*8 + (k&7)
// Fragment ds_read_b128 (16 rows, chunk=quad) is conflict-free
// (each 16B-slot position hit 2x per quad, distinct lines -- same
// construction as k64, measured 0 conflicts).
// Image array: [row-tile][k-tile(32 of them, K=1024)] -> tile idx = rt*32+kt.
// ---------------------------------------------------------------------------

// ---------------------------------------------------------------------------
// convert fp32 matrix (rows x 1024, row-major) -> hi/lo k32 images.
// one block per 4 KB tile; blockIdx.x = rt*32 + kt. Linear 16B writes.
// ---------------------------------------------------------------------------
__global__ __launch_bounds__(256)
void convert_img(const float* __restrict__ src, u16* __restrict__ dh, u16* __restrict__ dl)
{
    const int tile = blockIdx.x;
    const int rt = tile >> 5, kt = tile & 31;
    const size_t tb = (size_t)tile * 2048;         // u16 elements
    const int ci = threadIdx.x;                    // 0..255, 8 el each
    const int l  = ci >> 3;                        // line 0..31
    const int ph = ci & 7;                         // phys slot
    const int s  = ph ^ (l & 7);                   // logical slot
    const int r  = (l << 1) | (s >> 2);            // source row in tile
    const int k0 = (s & 3) << 3;                   // source k base
    const float* sp = src + ((size_t)(rt * 64 + r)) * 1024 + kt * 32 + k0;
    const float4 f0 = *(const float4*)sp;
    const float4 f1 = *(const float4*)(sp + 4);
    const float vals[8] = {f0.x, f0.y, f0.z, f0.w, f1.x, f1.y, f1.z, f1.w};
    __align__(16) short hs[8];
    __align__(16) short ls[8];
    #pragma unroll
    for (int j = 0; j < 8; ++j) {
        const u16 h = f2bf(vals[j]);
        hs[j] = (short)h;
        ls[j] = (short)f2bf(vals[j] - bf2f(h));
    }
    *(bf16x8*)(dh + tb + ci * 8) = *(const bf16x8*)hs;
    *(bf16x8*)(dl + tb + ci * 8) = *(const bf16x8*)ls;
}

// ---------------------------------------------------------------------------
// MFMA GEMM, hi/lo 3-product bf16, pure-DMA, PIPELINED (round 9):
// BM=256, BN=128, BK=32; 8 waves (512 thr) in 4x2; wave out 64x64 (4x4 acc).
// LDS: 2 x 12 k32-tiles (0-3 Ahi, 4-7 Alo, 8-9 Bhi, 10-11 Blo) = 96 KB dbuf.
// Per K-tile: {16 ds_read_b128 -> issue 6-gload prefetch(next) -> 48 MFMA ->
// ONE __syncthreads}. Prefetch latency hides under ~1900 cyc of MFMA; the
// barrier's implicit vmcnt(0) is then free. Grid rounds exact:
// QKV 768 = 3x256 CU, proj 256 = 1x256.
// Epilogue identical to the 128^2 version (same m/n formulas).
// ---------------------------------------------------------------------------
template<int MODE>
__global__ __launch_bounds__(512, 2)
void gemm_mfma(const u16* __restrict__ AIh, const u16* __restrict__ AIl,
               const u16* __restrict__ BIh, const u16* __restrict__ BIl,
               const float* __restrict__ bias, float* __restrict__ Cout,
               u16* __restrict__ qh, u16* __restrict__ ql,
               u16* __restrict__ kh,
               u16* __restrict__ vh, u16* __restrict__ vl)
{
    __shared__ __align__(16) u16 sT[2][12][2048];  // 96 KB

    const int tid = threadIdx.x, lane = tid & 63, w = tid >> 6;  // 8 waves
    const int quad = lane >> 4, l15 = lane & 15;
    const int m0  = blockIdx.x * 256;
    const int n0  = blockIdx.y * 128;
    const int mt0 = blockIdx.x * 4;                // A row-tile base (64-row)
    const int nt0 = blockIdx.y * 2;                // B row-tile base
    const int rw  = w >> 1;                        // 0..3: wave's 64-row slab
    const int cw  = w & 1;                         // 0..1: wave's 64-col slab

    // staging: 48 KB/buffer = 48 x 1KB chunks; chunk g = w*6+it.
    // tile t = g>>2 (0-3 Ahi, 4-7 Alo, 8-9 Bhi, 10-11 Blo), quarter = g&3.
    const u16* srcq[6];
    #pragma unroll
    for (int it = 0; it < 6; ++it) {
        const int g = w * 6 + it;
        const int t = g >> 2, qtr = g & 3;
        const u16* img = (t < 4) ? AIh : (t < 8) ? AIl : (t < 10) ? BIh : BIl;
        const int rtile = (t < 8) ? (mt0 + (t & 3)) : (nt0 + (t & 1));
        srcq[it] = img + (size_t)rtile * (32 * 2048) + qtr * 512 + lane * 8;
    }

    f32x4 acc[4][4];
    #pragma unroll
    for (int i = 0; i < 4; ++i)
        #pragma unroll
        for (int j = 0; j < 4; ++j)
            acc[i][j] = (f32x4){0.f, 0.f, 0.f, 0.f};

    // prologue: stage K-tile 0 into buffer 0
    #pragma unroll
    for (int it = 0; it < 6; ++it)
        gload_lds16(srcq[it], (char*)&sT[0][0][0] + (w * 6 + it) * 1024);
    __syncthreads();

    #pragma unroll 2
    for (int kt = 0; kt < 32; ++kt) {
        const int cur = kt & 1;
        // ---- fragment loads FIRST (no vmem in flight -> no forced vmcnt) ----
        bf16x8 aH[4], aL[4], bH[4], bL[4];
        #pragma unroll
        for (int i = 0; i < 4; ++i) {
            const int r = i * 16 + l15, l = r >> 1;
            const int off = l * 64 + (((((r & 1) << 2) + quad) ^ (l & 7)) << 3);
            aH[i] = *(const bf16x8*)&sT[cur][rw][off];
            aL[i] = *(const bf16x8*)&sT[cur][4 + rw][off];
        }
        #pragma unroll
        for (int j = 0; j < 4; ++j) {
            const int r = j * 16 + l15, l = r >> 1;
            const int off = l * 64 + (((((r & 1) << 2) + quad) ^ (l & 7)) << 3);
            bH[j] = *(const bf16x8*)&sT[cur][8 + cw][off];
            bL[j] = *(const bf16x8*)&sT[cur][10 + cw][off];
        }
        // ---- issue next-tile DMA (overlaps the MFMA cluster below) ----
        if (kt < 31) {
            #pragma unroll
            for (int it = 0; it < 6; ++it)
                gload_lds16(srcq[it] + (size_t)(kt + 1) * 2048,
                            (char*)&sT[cur ^ 1][0][0] + (w * 6 + it) * 1024);
        }
        // ---- 48 MFMA ----
        __builtin_amdgcn_s_setprio(1);
        #pragma unroll
        for (int i = 0; i < 4; ++i)
            #pragma unroll
            for (int j = 0; j < 4; ++j) {
                acc[i][j] = __builtin_amdgcn_mfma_f32_16x16x32_bf16(aL[i], bH[j], acc[i][j], 0, 0, 0);
                acc[i][j] = __builtin_amdgcn_mfma_f32_16x16x32_bf16(aH[i], bL[j], acc[i][j], 0, 0, 0);
                acc[i][j] = __builtin_amdgcn_mfma_f32_16x16x32_bf16(aH[i], bH[j], acc[i][j], 0, 0, 0);
            }
        __builtin_amdgcn_s_setprio(0);
        // single barrier per K-tile: drains prefetch (vmcnt(0)) + publishes
        // "all reads of cur done" so next iter may DMA into cur.
        __syncthreads();
    }

    // ---- epilogue (identical formulas to the 128^2 kernel) ----
    const int fbase = n0 + cw * 64;                // 64-aligned
    float bj[4];
    #pragma unroll
    for (int j = 0; j < 4; ++j) bj[j] = bias[fbase + j * 16 + l15];

    if (MODE == 0) {
        const int cR = fbase >> 10;                // 0=q 1=k 2=v (uniform per wave)
        const int hh = (fbase >> 6) & 15;
        #pragma unroll
        for (int i = 0; i < 4; ++i)
            #pragma unroll
            for (int j = 0; j < 4; ++j)
                #pragma unroll
                for (int reg = 0; reg < 4; ++reg) {
                    float val = acc[i][j][reg] + bj[j];
                    const int m = m0 + rw * 64 + i * 16 + quad * 4 + reg;
                    const int d = j * 16 + l15;
                    const int bb = m >> 11, s = m & 2047;
                    const int bh = bb * 16 + hh;
                    // q scale = 0.125 * log2(e): softmax uses exp2 directly.
                    if (cR == 0) val *= 0.18033688011112042f;
                    const u16 h = f2bf(val);
                    if (cR == 0) {
                        const u16 lo = f2bf(val - bf2f(h));
                        const size_t idx = ((size_t)bh * 2048 + s) * 64 + d;
                        qh[idx] = h; ql[idx] = lo;
                    } else if (cR == 1) {
                        // k-lo not consumed (2-product QK) -> only hi written (k64 image)
                        const size_t tile = (size_t)bh * 32 + (s >> 6);
                        const int r = s & 63;
                        const size_t off = (tile << 12) + r * 64 + (((d >> 3) ^ (r & 7)) << 3) + (d & 7);
                        kh[off] = h;
                    } else {
                        const u16 lo = f2bf(val - bf2f(h));
                        const size_t tile = (size_t)bh * 32 + (s >> 6);
                        const size_t off = (tile << 12) + d * 64 + ((((s & 63) >> 3) ^ (d & 7)) << 3) + (s & 7);
                        vh[off] = h; vl[off] = lo;
                    }
                }
    } else {
        #pragma unroll
        for (int i = 0; i < 4; ++i)
            #pragma unroll
            for (int j = 0; j < 4; ++j)
                #pragma unroll
                for (int reg = 0; reg < 4; ++reg) {
                    const int m = m0 + rw * 64 + i * 16 + quad * 4 + reg;
                    const int f = fbase + j * 16 + l15;
                    Cout[(size_t)m * 1024 + f] = acc[i][j][reg] + bj[j];
                }
    }
}

// ---------------------------------------------------------------------------
// MFMA flash attention -- UNCHANGED core (round-4 verified, 163.5 us);
// only the o epilogue now writes the k32 image format for the proj GEMM.
// ---------------------------------------------------------------------------
__global__ __launch_bounds__(256, 3)
void attn_mfma(const u16* __restrict__ qh, const u16* __restrict__ ql,
               const u16* __restrict__ kh,
               const u16* __restrict__ vh, const u16* __restrict__ vl,
               u16* __restrict__ oh, u16* __restrict__ ol)
{
    __shared__ __align__(16) u16 KV[3][4096];     // Khi Vthi Vtlo (24 KB, k64 images)

    const int tid  = threadIdx.x;
    const int lane = tid & 63, w = tid >> 6;
    const int quad = lane >> 4, l15 = lane & 15;
    const int bh = blockIdx.y;
    const int q0 = blockIdx.x * 128 + w * 32;

    bf16x8 Qf[2][2][2];
    #pragma unroll
    for (int qs = 0; qs < 2; ++qs)
        #pragma unroll
        for (int kk = 0; kk < 2; ++kk) {
            const size_t idx = ((size_t)bh * S_ + q0 + qs * 16 + l15) * 64 + kk * 32 + quad * 8;
            Qf[qs][kk][0] = *(const bf16x8*)(qh + idx);
            Qf[qs][kk][1] = *(const bf16x8*)(ql + idx);
        }

    f32x4 O[2][4];
    float l_part[2] = {0.f, 0.f};
    #pragma unroll
    for (int qs = 0; qs < 2; ++qs)
        #pragma unroll
        for (int ds = 0; ds < 4; ++ds)
            O[qs][ds] = (f32x4){0.f, 0.f, 0.f, 0.f};

    const char* gk[3] = {(const char*)kh, (const char*)vh, (const char*)vl};

    for (int kt = 0; kt < S_ / 64; ++kt) {
        __syncthreads();
        const size_t tb = (((size_t)bh * 32 + kt) << 13);
        #pragma unroll
        for (int a = 0; a < 3; ++a)
            #pragma unroll
            for (int it = 0; it < 2; ++it) {
                const int off = w * 2048 + it * 1024;
                gload_lds16(gk[a] + tb + off + lane * 16, (char*)&KV[a][0] + off);
            }
        __syncthreads();

        // ---- swapped QK:  Ssw[m=k][n=q],  init = -16*log2(e) (fixed max) ----
        f32x4 S[2][4];
        #pragma unroll
        for (int qs = 0; qs < 2; ++qs)
            #pragma unroll
            for (int ks = 0; ks < 4; ++ks)
                S[qs][ks] = (f32x4){-23.083120654223414f, -23.083120654223414f,
                                    -23.083120654223414f, -23.083120654223414f};

        __builtin_amdgcn_s_setprio(1);
        #pragma unroll
        for (int ks = 0; ks < 4; ++ks) {
            const int r = ks * 16 + l15;
            #pragma unroll
            for (int kk = 0; kk < 2; ++kk) {
                const int c = (kk * 4 + quad) ^ (r & 7);
                const bf16x8 Kh = *(const bf16x8*)&KV[0][r * 64 + c * 8];
                #pragma unroll
                for (int qs = 0; qs < 2; ++qs) {
                    S[qs][ks] = __builtin_amdgcn_mfma_f32_16x16x32_bf16(Kh, Qf[qs][kk][1], S[qs][ks], 0, 0, 0);
                    S[qs][ks] = __builtin_amdgcn_mfma_f32_16x16x32_bf16(Kh, Qf[qs][kk][0], S[qs][ks], 0, 0, 0);
                }
            }
        }
        __builtin_amdgcn_s_setprio(0);

        // ---- softmax + in-register transpose to PV operand layout ----
        u32 PA[2][2][4];     // [qs][kk][word]
        #pragma unroll
        for (int qs = 0; qs < 2; ++qs) {
            float lsum = 0.f;
            u32 PK[4][2];
            #pragma unroll
            for (int ks = 0; ks < 4; ++ks) {
                const float p0 = __builtin_exp2f(S[qs][ks][0]);
                const float p1 = __builtin_exp2f(S[qs][ks][1]);
                const float p2 = __builtin_exp2f(S[qs][ks][2]);
                const float p3 = __builtin_exp2f(S[qs][ks][3]);
                lsum += (p0 + p1) + (p2 + p3);
                PK[ks][0] = cvtpk_bf16(p0, p1);
                PK[ks][1] = cvtpk_bf16(p2, p3);
            }
            l_part[qs] += lsum;
            #pragma unroll
            for (int kk = 0; kk < 2; ++kk) {
                const u32x2 t0 = __builtin_amdgcn_permlane32_swap(PK[2 * kk][0], PK[2 * kk + 1][0], false, false);
                const u32x2 w02 = __builtin_amdgcn_permlane16_swap(t0.x, t0.y, false, false);
                const u32x2 t1 = __builtin_amdgcn_permlane32_swap(PK[2 * kk][1], PK[2 * kk + 1][1], false, false);
                const u32x2 w13 = __builtin_amdgcn_permlane16_swap(t1.x, t1.y, false, false);
                PA[qs][kk][0] = w02.x;
                PA[qs][kk][1] = w13.x;
                PA[qs][kk][2] = w02.y;
                PA[qs][kk][3] = w13.y;
            }
        }

        // ---- swapped PV:  O^T += Vt x PA  (two products: Vlo, Vhi) ----
        __builtin_amdgcn_s_setprio(1);
        #pragma unroll
        for (int kk = 0; kk < 2; ++kk) {
            union { u32 w4[4]; bf16x8 v; } pu0, pu1;
            #pragma unroll
            for (int c = 0; c < 4; ++c) { pu0.w4[c] = PA[0][kk][c]; pu1.w4[c] = PA[1][kk][c]; }
            const bf16x8 paf[2] = {pu0.v, pu1.v};
            #pragma unroll
            for (int ds = 0; ds < 4; ++ds) {
                const int r = ds * 16 + l15;
                const int c = (kk * 4 + quad) ^ (r & 7);
                const bf16x8 Vh = *(const bf16x8*)&KV[1][r * 64 + c * 8];
                const bf16x8 Vl = *(const bf16x8*)&KV[2][r * 64 + c * 8];
                #pragma unroll
                for (int qs = 0; qs < 2; ++qs) {
                    O[qs][ds] = __builtin_amdgcn_mfma_f32_16x16x32_bf16(Vl, paf[qs], O[qs][ds], 0, 0, 0);
                    O[qs][ds] = __builtin_amdgcn_mfma_f32_16x16x32_bf16(Vh, paf[qs], O[qs][ds], 0, 0, 0);
                }
            }
        }
        __builtin_amdgcn_s_setprio(0);
    }

    // ---- l reduction across quads ----
    float linv[2];
    #pragma unroll
    for (int qs = 0; qs < 2; ++qs) {
        float rs = l_part[qs];
        rs += __shfl_xor(rs, 16);
        rs += __shfl_xor(rs, 32);
        linv[qs] = 1.f / rs;
    }

    // ---- epilogue: lane holds O[d = ds*16+quad*4+reg][q = l15];
    //      write k32 image format (proj GEMM input) ----
    const int bb = bh >> 4, hh = bh & 15;
    #pragma unroll
    for (int qs = 0; qs < 2; ++qs) {
        const float inv = linv[qs];
        const int s = q0 + qs * 16 + l15;
        const int m = bb * 2048 + s;
        const int mt = m >> 6, r = m & 63;
        const int l = r >> 1;
        const size_t tb0 = ((size_t)(mt * 32 + hh * 2)) * 2048;
        #pragma unroll
        for (int ds = 0; ds < 4; ++ds) {
            const int d0 = ds * 16 + quad * 4;     // 4 consecutive d per thread
            const float v0 = O[qs][ds][0] * inv;
            const float v1 = O[qs][ds][1] * inv;
            const float v2 = O[qs][ds][2] * inv;
            const float v3 = O[qs][ds][3] * inv;
            const u32 h01 = cvtpk_bf16(v0, v1);
            const u32 h23 = cvtpk_bf16(v2, v3);
            const float r0 = v0 - bf2f((u16)h01);
            const float r1 = v1 - bf2f((u16)(h01 >> 16));
            const float r2 = v2 - bf2f((u16)h23);
            const float r3 = v3 - bf2f((u16)(h23 >> 16));
            const u32 l01 = cvtpk_bf16(r0, r1);
            const u32 l23 = cvtpk_bf16(r2, r3);
            const int c  = (d0 & 31) >> 3;
            const int ph = (((r & 1) << 2) + c) ^ (l & 7);
            const size_t off = tb0 + (size_t)(d0 >> 5) * 2048 + l * 64 + ph * 8 + (d0 & 7);
            *(u32x2*)(oh + off) = (u32x2){h01, h23};
            *(u32x2*)(ol + off) = (u32x2){l01, l23};
        }
    }
}

// ---------------------------------------------------------------------------
extern "C" void kernel_launch(void* const* d_in, const int* in_sizes, int n_in,
                              void* d_out, int out_size, void* d_ws, size_t ws_size,
                              hipStream_t stream) {
    const float* x      = (const float*)d_in[0];
    const float* w_qkv  = (const float*)d_in[1];
    const float* b_qkv  = (const float*)d_in[2];
    const float* w_proj = (const float*)d_in[3];
    const float* b_proj = (const float*)d_in[4];
    float* out = (float*)d_out;

    // ws (130 MB, < proven-safe 134 MB):
    //   [0..5NE_)        qh ql kh vh vl
    //   [5NE_..7NE_)     xh xl (phase 0-1)  -> aliased by oh ol (phase 2+)
    //   [7NE_..)         wqh wql (6.29M u16, phase 0-1) -> aliased by wph wpl
    u16* qh  = (u16*)d_ws;
    u16* ql  = qh + NE_;
    u16* kh  = ql + NE_;
    u16* vh  = kh + NE_;
    u16* vl  = vh + NE_;
    u16* xh  = vl + NE_;
    u16* xl  = xh + NE_;
    u16* wqh = xl + NE_;
    u16* wql = wqh + (size_t)3 * 1024 * 1024;
    u16* oh  = xh;                         // alias (x dead after QKV)
    u16* ol  = xl;
    u16* wph = wqh;                        // alias (wq dead after QKV)
    u16* wpl = wph + (size_t)1024 * 1024;

    // Phase 0: one-time conversions to hi/lo k32 images (4 KB tiles)
    convert_img<<<128 * 32, 256, 0, stream>>>(x, xh, xl);        // 4096 tiles
    convert_img<<<48 * 32, 256, 0, stream>>>(w_qkv, wqh, wql);   // 1536 tiles

    {   // Phase 1: QKV GEMM (pipelined 256x128): x @ w_qkv^T + b -> q/k/v
        dim3 grid(M_ / 256, (3 * E_) / 128);   // 32 x 24 = 768 = 3x256 CUs
        gemm_mfma<0><<<grid, 512, 0, stream>>>(xh, xl, wqh, wql,
                                               b_qkv, nullptr, qh, ql, kh, vh, vl);
    }
    {   // Phase 2: MFMA flash attention -> o k32 images (overwrites x images)
        dim3 grid(S_ / 128, B_ * H_);          // 16 x 64
        attn_mfma<<<grid, 256, 0, stream>>>(qh, ql, kh, vh, vl, oh, ol);
    }
    // Phase 2.5: convert w_proj (overwrites wq images)
    convert_img<<<16 * 32, 256, 0, stream>>>(w_proj, wph, wpl);  // 512 tiles
    {   // Phase 3: proj GEMM (pipelined 256x128): o @ w_proj^T + b -> out
        dim3 grid(M_ / 256, E_ / 128);         // 32 x 8 = 256 = 1x256 CUs
        gemm_mfma<1><<<grid, 512, 0, stream>>>(oh, ol, wph, wpl,
                                               b_proj, out, nullptr, nullptr, nullptr,
                                               nullptr, nullptr);
    }
}